// Round 1
// baseline (914.880 us; speedup 1.0000x reference)
//
#include <hip/hip_runtime.h>

// Problem constants
constexpr int BATCH = 4;
constexpr int SEQQ  = 1024;
constexpr int SEQK  = 2048;
constexpr int DIM   = 1024;
constexpr int NH    = 16;
constexpr int DH    = 64;
constexpr int RQ    = BATCH * SEQQ;          // 4096 q rows
constexpr int RK    = BATCH * SEQK;          // 8192 k rows (== v rows)
constexpr int RTOT  = RQ + 2 * RK;           // 20480
constexpr float LN_EPS = 1e-5f;

// ---------------------------------------------------------------------------
// K0: per-row LayerNorm stats (mean, rstd) for q,k,v rows. One block per row.
// ---------------------------------------------------------------------------
__global__ void __launch_bounds__(256) ln_stats_kernel(
    const float* __restrict__ q, const float* __restrict__ k,
    const float* __restrict__ v, float* __restrict__ stats) {
  int row = blockIdx.x;
  const float* src;
  if (row < RQ)            src = q + (size_t)row * DIM;
  else if (row < RQ + RK)  src = k + (size_t)(row - RQ) * DIM;
  else                     src = v + (size_t)(row - RQ - RK) * DIM;
  int t = threadIdx.x;
  float4 x = ((const float4*)src)[t];
  float s  = x.x + x.y + x.z + x.w;
  float s2 = x.x * x.x + x.y * x.y + x.z * x.z + x.w * x.w;
  for (int off = 32; off; off >>= 1) {
    s  += __shfl_down(s, off);
    s2 += __shfl_down(s2, off);
  }
  __shared__ float ls[4], ls2[4];
  int wid = t >> 6;
  if ((t & 63) == 0) { ls[wid] = s; ls2[wid] = s2; }
  __syncthreads();
  if (t == 0) {
    float S1 = ls[0] + ls[1] + ls[2] + ls[3];
    float S2 = ls2[0] + ls2[1] + ls2[2] + ls2[3];
    float mu  = S1 / DIM;
    float var = S2 / DIM - mu * mu;
    stats[2 * row]     = mu;
    stats[2 * row + 1] = rsqrtf(var + LN_EPS);
  }
}

// ---------------------------------------------------------------------------
// K1/K5: 128x128 tiled fp32 GEMM, K=DIM=1024, N=DIM=1024, BK=16.
// 256 threads, 8x8 micro-tile per thread. Optional fused LayerNorm on A rows
// (mu/rstd from stats, per-col gamma/beta), optional bias on output.
// LDS stride 132 (=128+4): bank-shift 4 per k-row -> conflict-free scattered
// A-transpose writes; 132%4==0 keeps float4 alignment for compute reads.
// ---------------------------------------------------------------------------
template <bool LN, bool BIAS>
__global__ void __launch_bounds__(256) gemm128(
    const float* __restrict__ A, const float* __restrict__ W,
    float* __restrict__ C,
    const float* __restrict__ stats,
    const float* __restrict__ gamma, const float* __restrict__ beta,
    const float* __restrict__ bias) {
  __shared__ float As[16][132];
  __shared__ float Bs[16][132];
  const int t   = threadIdx.x;
  const int row0 = blockIdx.x * 128;
  const int col0 = blockIdx.y * 128;

  // A-load mapping: 2 threads per row, 8 cols each (two float4)
  const int lr = t >> 1;             // 0..127
  const int lc = (t & 1) * 8;        // 0 or 8
  // B-load mapping: 16 threads per k-row, 8 cols each
  const int wr = t >> 4;             // 0..15
  const int wc = (t & 15) * 8;       // 0..120
  // compute mapping
  const int n0 = (t & 15) * 8;
  const int m0 = (t >> 4) * 8;

  float mu = 0.f, rs = 0.f;
  if (LN) {
    mu = stats[2 * (row0 + lr)];
    rs = stats[2 * (row0 + lr) + 1];
  }

  float acc[8][8];
#pragma unroll
  for (int i = 0; i < 8; i++)
#pragma unroll
    for (int j = 0; j < 8; j++) acc[i][j] = 0.f;

  const float* Arow = A + (size_t)(row0 + lr) * DIM;

  for (int kt = 0; kt < DIM / 16; ++kt) {
    const int k0 = kt * 16;
    // global loads (overlap with previous tile's compute)
    float av[8];
    *(float4*)&av[0] = *(const float4*)(Arow + k0 + lc);
    *(float4*)&av[4] = *(const float4*)(Arow + k0 + lc + 4);
    if (LN) {
      float gv[8], bv[8];
      *(float4*)&gv[0] = *(const float4*)(gamma + k0 + lc);
      *(float4*)&gv[4] = *(const float4*)(gamma + k0 + lc + 4);
      *(float4*)&bv[0] = *(const float4*)(beta + k0 + lc);
      *(float4*)&bv[4] = *(const float4*)(beta + k0 + lc + 4);
#pragma unroll
      for (int j = 0; j < 8; j++) av[j] = (av[j] - mu) * rs * gv[j] + bv[j];
    }
    const float* Wrow = W + (size_t)(k0 + wr) * DIM + col0 + wc;
    float4 w0 = *(const float4*)(Wrow);
    float4 w1 = *(const float4*)(Wrow + 4);

    __syncthreads();  // previous tile's compute done
#pragma unroll
    for (int j = 0; j < 8; j++) As[lc + j][lr] = av[j];
    *(float4*)&Bs[wr][wc]     = w0;
    *(float4*)&Bs[wr][wc + 4] = w1;
    __syncthreads();  // stores visible

#pragma unroll
    for (int kk = 0; kk < 16; kk++) {
      float a[8], b[8];
      *(float4*)&a[0] = *(const float4*)&As[kk][m0];
      *(float4*)&a[4] = *(const float4*)&As[kk][m0 + 4];
      *(float4*)&b[0] = *(const float4*)&Bs[kk][n0];
      *(float4*)&b[4] = *(const float4*)&Bs[kk][n0 + 4];
#pragma unroll
      for (int i = 0; i < 8; i++)
#pragma unroll
        for (int j = 0; j < 8; j++) acc[i][j] = fmaf(a[i], b[j], acc[i][j]);
    }
  }

  if (BIAS) {
    float bv[8];
    *(float4*)&bv[0] = *(const float4*)(bias + col0 + n0);
    *(float4*)&bv[4] = *(const float4*)(bias + col0 + n0 + 4);
#pragma unroll
    for (int i = 0; i < 8; i++)
#pragma unroll
      for (int j = 0; j < 8; j++) acc[i][j] += bv[j];
  }
#pragma unroll
  for (int i = 0; i < 8; i++) {
    float* Crow = C + (size_t)(row0 + m0 + i) * DIM + col0 + n0;
    *(float4*)Crow       = *(float4*)&acc[i][0];
    *((float4*)Crow + 1) = *(float4*)&acc[i][4];
  }
}

// ---------------------------------------------------------------------------
// K2: per-(row,head) inverse L2 norms of f_q and f_k. One block per f row.
// head = group of 16 threads (16 threads x 4 floats = 64 cols).
// ---------------------------------------------------------------------------
__global__ void __launch_bounds__(256) norms_kernel(
    const float* __restrict__ f, float* __restrict__ rq, float* __restrict__ rk) {
  int row = blockIdx.x;  // 0..RQ+RK-1 (q rows then k rows of f)
  int t = threadIdx.x;
  float4 x = ((const float4*)(f + (size_t)row * DIM))[t];
  float s2 = x.x * x.x + x.y * x.y + x.z * x.z + x.w * x.w;
  s2 += __shfl_xor(s2, 1);
  s2 += __shfl_xor(s2, 2);
  s2 += __shfl_xor(s2, 4);
  s2 += __shfl_xor(s2, 8);
  if ((t & 15) == 0) {
    int h = t >> 4;
    float inv = rsqrtf(s2);  // 1/||.||  (eps=1e-8 in denom is negligible)
    if (row < RQ) rq[(size_t)row * NH + h] = inv;
    else          rk[(size_t)(row - RQ) * NH + h] = inv;
  }
}

// ---------------------------------------------------------------------------
// K3: per-(b,h) S = sum_m (f_k[m]/kn[m]) outer f_v[m]  (64x64).
// grid (BATCH*NH, 4): each block does 512 m, staged 32 at a time in LDS,
// 4x4 outputs per thread, atomicAdd partials (S pre-zeroed).
// ---------------------------------------------------------------------------
__global__ void __launch_bounds__(256) s_kernel(
    const float* __restrict__ f, const float* __restrict__ rk,
    float* __restrict__ S) {
  const int bh = blockIdx.x;
  const int b = bh >> 4, h = bh & 15;
  const int mbase = blockIdx.y * 512;
  const int t = threadIdx.x;
  __shared__ float ks[32][68];
  __shared__ float vs[32][68];
  const int lm   = t >> 3;        // 0..31
  const int lseg = (t & 7) * 8;   // 0..56
  const int d1 = (t & 15) * 4;
  const int d2 = (t >> 4) * 4;
  float acc[4][4] = {{0.f}};
  const float* fk_base = f + ((size_t)RQ + (size_t)b * SEQK) * DIM + h * DH;
  const float* fv_base = f + ((size_t)RQ + RK + (size_t)b * SEQK) * DIM + h * DH;

  for (int sub = 0; sub < 16; ++sub) {
    const int m = mbase + sub * 32 + lm;
    const float scale = rk[(size_t)(b * SEQK + m) * NH + h];
    const float* kr = fk_base + (size_t)m * DIM + lseg;
    const float* vr = fv_base + (size_t)m * DIM + lseg;
    float4 k0 = *(const float4*)kr;
    float4 k1 = *(const float4*)(kr + 4);
    float4 v0 = *(const float4*)vr;
    float4 v1 = *(const float4*)(vr + 4);
    __syncthreads();
    ks[lm][lseg + 0] = k0.x * scale; ks[lm][lseg + 1] = k0.y * scale;
    ks[lm][lseg + 2] = k0.z * scale; ks[lm][lseg + 3] = k0.w * scale;
    ks[lm][lseg + 4] = k1.x * scale; ks[lm][lseg + 5] = k1.y * scale;
    ks[lm][lseg + 6] = k1.z * scale; ks[lm][lseg + 7] = k1.w * scale;
    *(float4*)&vs[lm][lseg]     = v0;
    *(float4*)&vs[lm][lseg + 4] = v1;
    __syncthreads();
#pragma unroll
    for (int mm = 0; mm < 32; ++mm) {
      float4 kk = *(const float4*)&ks[mm][d1];
      float4 vv = *(const float4*)&vs[mm][d2];
      acc[0][0] = fmaf(kk.x, vv.x, acc[0][0]);
      acc[0][1] = fmaf(kk.x, vv.y, acc[0][1]);
      acc[0][2] = fmaf(kk.x, vv.z, acc[0][2]);
      acc[0][3] = fmaf(kk.x, vv.w, acc[0][3]);
      acc[1][0] = fmaf(kk.y, vv.x, acc[1][0]);
      acc[1][1] = fmaf(kk.y, vv.y, acc[1][1]);
      acc[1][2] = fmaf(kk.y, vv.z, acc[1][2]);
      acc[1][3] = fmaf(kk.y, vv.w, acc[1][3]);
      acc[2][0] = fmaf(kk.z, vv.x, acc[2][0]);
      acc[2][1] = fmaf(kk.z, vv.y, acc[2][1]);
      acc[2][2] = fmaf(kk.z, vv.z, acc[2][2]);
      acc[2][3] = fmaf(kk.z, vv.w, acc[2][3]);
      acc[3][0] = fmaf(kk.w, vv.x, acc[3][0]);
      acc[3][1] = fmaf(kk.w, vv.y, acc[3][1]);
      acc[3][2] = fmaf(kk.w, vv.z, acc[3][2]);
      acc[3][3] = fmaf(kk.w, vv.w, acc[3][3]);
    }
  }
  float* Sp = S + (size_t)bh * DH * DH;
#pragma unroll
  for (int i = 0; i < 4; i++)
#pragma unroll
    for (int j = 0; j < 4; j++)
      atomicAdd(&Sp[(d1 + i) * DH + (d2 + j)], acc[i][j]);
}

// ---------------------------------------------------------------------------
// K4: out_head: ao[b, n, h*64+d2] = (f_q[b,n,h,:] @ S[b,h]) * rq[b,n,h]
// grid (BATCH*NH, SEQQ/64). Stage S (64x64) and a 64-row Q tile in LDS.
// ---------------------------------------------------------------------------
__global__ void __launch_bounds__(256) outhead_kernel(
    const float* __restrict__ f, const float* __restrict__ S,
    const float* __restrict__ rq, float* __restrict__ ao) {
  const int bh = blockIdx.x;
  const int b = bh >> 4, h = bh & 15;
  const int nbase = blockIdx.y * 64;
  const int t = threadIdx.x;
  __shared__ float Sl[64][68];
  __shared__ float Ql[64][68];
  {
    const int r = t >> 2;            // 0..63
    const int seg = (t & 3) * 16;    // 0,16,32,48
    const float* Sp = S + (size_t)bh * DH * DH + r * DH + seg;
    const float* Qp = f + ((size_t)b * SEQQ + nbase + r) * DIM + h * DH + seg;
#pragma unroll
    for (int c = 0; c < 4; c++) {
      *(float4*)&Sl[r][seg + 4 * c] = ((const float4*)Sp)[c];
      *(float4*)&Ql[r][seg + 4 * c] = ((const float4*)Qp)[c];
    }
  }
  __syncthreads();
  const int d2 = (t & 15) * 4;
  const int g  = t >> 4;  // 0..15
#pragma unroll
  for (int i = 0; i < 4; ++i) {
    const int n = i * 16 + g;
    float4 acc = {0.f, 0.f, 0.f, 0.f};
#pragma unroll 8
    for (int d1 = 0; d1 < 64; ++d1) {
      float qv = Ql[n][d1];
      float4 sv = *(const float4*)&Sl[d1][d2];
      acc.x = fmaf(qv, sv.x, acc.x);
      acc.y = fmaf(qv, sv.y, acc.y);
      acc.z = fmaf(qv, sv.z, acc.z);
      acc.w = fmaf(qv, sv.w, acc.w);
    }
    const float r = rq[((size_t)b * SEQQ + nbase + n) * NH + h];
    acc.x *= r; acc.y *= r; acc.z *= r; acc.w *= r;
    *(float4*)(ao + ((size_t)b * SEQQ + nbase + n) * DIM + h * DH + d2) = acc;
  }
}

// ---------------------------------------------------------------------------
extern "C" void kernel_launch(void* const* d_in, const int* in_sizes, int n_in,
                              void* d_out, int out_size, void* d_ws, size_t ws_size,
                              hipStream_t stream) {
  const float* q     = (const float*)d_in[0];
  const float* k     = (const float*)d_in[1];
  const float* v     = (const float*)d_in[2];
  const float* gamma = (const float*)d_in[3];
  const float* beta  = (const float*)d_in[4];
  const float* W_in  = (const float*)d_in[5];
  const float* W_out = (const float*)d_in[6];
  const float* b_out = (const float*)d_in[7];
  float* out = (float*)d_out;

  // workspace layout (floats):
  float* ws    = (float*)d_ws;
  float* f     = ws;                              // RTOT*DIM   (80 MB)
  float* stats = f + (size_t)RTOT * DIM;          // 2*RTOT
  float* rq    = stats + 2 * (size_t)RTOT;        // RQ*NH
  float* rk    = rq + (size_t)RQ * NH;            // RK*NH
  float* S     = rk + (size_t)RK * NH;            // BATCH*NH*DH*DH (1 MB)
  // attn_out aliases the f_k region (dead after s_kernel): 16 MB fits in 32 MB
  float* ao    = f + (size_t)RQ * DIM;

  hipMemsetAsync(S, 0, (size_t)BATCH * NH * DH * DH * sizeof(float), stream);

  ln_stats_kernel<<<RTOT, 256, 0, stream>>>(q, k, v, stats);

  // projections: f = LN(t) @ W_in  (q rows, then k rows, then v rows of f)
  gemm128<true, false><<<dim3(RQ / 128, DIM / 128), 256, 0, stream>>>(
      q, W_in, f, stats, gamma, beta, nullptr);
  gemm128<true, false><<<dim3(RK / 128, DIM / 128), 256, 0, stream>>>(
      k, W_in, f + (size_t)RQ * DIM, stats + 2 * (size_t)RQ, gamma, beta, nullptr);
  gemm128<true, false><<<dim3(RK / 128, DIM / 128), 256, 0, stream>>>(
      v, W_in, f + (size_t)(RQ + RK) * DIM, stats + 2 * (size_t)(RQ + RK),
      gamma, beta, nullptr);

  norms_kernel<<<RQ + RK, 256, 0, stream>>>(f, rq, rk);

  s_kernel<<<dim3(BATCH * NH, 4), 256, 0, stream>>>(f, rk, S);

  outhead_kernel<<<dim3(BATCH * NH, SEQQ / 64), 256, 0, stream>>>(f, S, rq, ao);

  // final: out = ao @ W_out + b_out
  gemm128<false, true><<<dim3(RQ / 128, DIM / 128), 256, 0, stream>>>(
      ao, W_out, out, nullptr, nullptr, nullptr, b_out);
}

// Round 2
// 283.593 us; speedup vs baseline: 3.2260x; 3.2260x over previous
//
#include <hip/hip_runtime.h>

// Problem constants
constexpr int BATCH = 4;
constexpr int SEQQ  = 1024;
constexpr int SEQK  = 2048;
constexpr int DIM   = 1024;
constexpr int NH    = 16;
constexpr int DH    = 64;
constexpr int RQ    = BATCH * SEQQ;          // 4096 q rows
constexpr int RK    = BATCH * SEQK;          // 8192 k rows (== v rows)
constexpr int RTOT  = RQ + 2 * RK;           // 20480
constexpr float LN_EPS = 1e-5f;

typedef _Float16 f16;
typedef __attribute__((ext_vector_type(8))) _Float16 f16x8;
typedef __attribute__((ext_vector_type(4))) float f32x4;

__device__ __forceinline__ void async16(const void* g, void* l) {
  __builtin_amdgcn_global_load_lds(
      (const __attribute__((address_space(1))) void*)g,
      (__attribute__((address_space(3))) void*)l, 16, 0, 0);
}

// ---------------------------------------------------------------------------
// K0: fused LayerNorm -> fp16 for q,k,v rows. One block per row.
// a_h[row] = ((x - mu) * rstd * gamma + beta) as fp16, rows: q | k | v.
// ---------------------------------------------------------------------------
__global__ void __launch_bounds__(256) ln_to_f16(
    const float* __restrict__ q, const float* __restrict__ k,
    const float* __restrict__ v, const float* __restrict__ gamma,
    const float* __restrict__ beta, f16* __restrict__ a_h) {
  int row = blockIdx.x;
  const float* src;
  if (row < RQ)            src = q + (size_t)row * DIM;
  else if (row < RQ + RK)  src = k + (size_t)(row - RQ) * DIM;
  else                     src = v + (size_t)(row - RQ - RK) * DIM;
  int t = threadIdx.x;
  float4 x = ((const float4*)src)[t];
  float s  = x.x + x.y + x.z + x.w;
  float s2 = x.x * x.x + x.y * x.y + x.z * x.z + x.w * x.w;
  for (int off = 32; off; off >>= 1) {
    s  += __shfl_down(s, off);
    s2 += __shfl_down(s2, off);
  }
  __shared__ float ls[4], ls2[4];
  __shared__ float smu, srs;
  int wid = t >> 6;
  if ((t & 63) == 0) { ls[wid] = s; ls2[wid] = s2; }
  __syncthreads();
  if (t == 0) {
    float S1 = ls[0] + ls[1] + ls[2] + ls[3];
    float S2 = ls2[0] + ls2[1] + ls2[2] + ls2[3];
    float mu  = S1 / DIM;
    float var = S2 / DIM - mu * mu;
    smu = mu;
    srs = rsqrtf(var + LN_EPS);
  }
  __syncthreads();
  float mu = smu, rs = srs;
  float4 g = ((const float4*)gamma)[t];
  float4 b = ((const float4*)beta)[t];
  union { f16 h[4]; uint2 u; } o;
  o.h[0] = (f16)((x.x - mu) * rs * g.x + b.x);
  o.h[1] = (f16)((x.y - mu) * rs * g.y + b.y);
  o.h[2] = (f16)((x.z - mu) * rs * g.z + b.z);
  o.h[3] = (f16)((x.w - mu) * rs * g.w + b.w);
  ((uint2*)(a_h + (size_t)row * DIM))[t] = o.u;
}

// ---------------------------------------------------------------------------
// K0b: transpose + fp16 convert of W_in and W_out (1024x1024 each).
// T[n][k] = W[k][n]. blockIdx.z selects the matrix.
// ---------------------------------------------------------------------------
__global__ void __launch_bounds__(256) transpose_f16(
    const float* __restrict__ W0, const float* __restrict__ W1,
    f16* __restrict__ T0, f16* __restrict__ T1) {
  const float* W = blockIdx.z ? W1 : W0;
  f16* T = blockIdx.z ? T1 : T0;
  __shared__ float tile[32][33];
  int tx = threadIdx.x & 31, ty = threadIdx.x >> 5;  // ty 0..7
  int k0 = blockIdx.x * 32, n0 = blockIdx.y * 32;
#pragma unroll
  for (int i = 0; i < 4; i++)
    tile[ty + 8 * i][tx] = W[(size_t)(k0 + ty + 8 * i) * DIM + n0 + tx];
  __syncthreads();
#pragma unroll
  for (int i = 0; i < 4; i++)
    T[(size_t)(n0 + ty + 8 * i) * DIM + k0 + tx] = (f16)tile[tx][ty + 8 * i];
}

// ---------------------------------------------------------------------------
// K1/K5: MFMA fp16 GEMM, C[M x 1024] = A[M x 1024] * Bt[1024 x 1024]^T.
// A row-major [M][K], Bt is N-major [N][K] (pre-transposed weights).
// 128x128 block tile, BK=32, 4 waves each computing a 64x64 quadrant as
// 4x4 grid of 16x16x32 MFMAs. global_load_lds width=16 staging (m97 recipe).
// ---------------------------------------------------------------------------
template <bool BIAS>
__global__ void __launch_bounds__(256) mfma_gemm(
    const f16* __restrict__ A, const f16* __restrict__ Bt,
    float* __restrict__ C, const float* __restrict__ bias) {
  __shared__ f16 As[128 * 32];
  __shared__ f16 Bs[128 * 32];
  const int t = threadIdx.x;
  const int wid = t >> 6;
  const int lane = t & 63;
  const int row0 = blockIdx.x * 128;
  const int col0 = blockIdx.y * 128;
  const int wm = (wid >> 1) * 64;   // wave's row quadrant
  const int wn = (wid & 1) * 64;    // wave's col quadrant

  // staging: wave w stages 32 rows of A and 32 rows of Bt.
  // LDS row = 32 f16 = 64 B; lane L -> row (L>>2), 16-B chunk (L&3).
  const f16* gA = A + (size_t)(row0 + 32 * wid + (lane >> 2)) * DIM + (lane & 3) * 8;
  const f16* gB = Bt + (size_t)(col0 + 32 * wid + (lane >> 2)) * DIM + (lane & 3) * 8;
  f16* lA = As + 32 * wid * 32;   // element base for this wave's A rows
  f16* lB = Bs + 32 * wid * 32;

  f32x4 acc[4][4];
#pragma unroll
  for (int i = 0; i < 4; i++)
#pragma unroll
    for (int j = 0; j < 4; j++) acc[i][j] = (f32x4){0.f, 0.f, 0.f, 0.f};

  const int mrow = lane & 15;      // fragment row/col within 16-tile
  const int kq   = (lane >> 4) * 8;  // fragment k-offset (quad*8)

  for (int kt = 0; kt < DIM / 32; ++kt) {
    if (kt) __syncthreads();       // frag reads of prev iter complete
    const int ko = kt * 32;
    async16(gA + ko,             lA);
    async16(gA + ko + 16 * DIM,  lA + 16 * 32);
    async16(gB + ko,             lB);
    async16(gB + ko + 16 * DIM,  lB + 16 * 32);
    __syncthreads();               // drains vmcnt: tiles visible

    f16x8 af[4], bf[4];
#pragma unroll
    for (int i = 0; i < 4; i++)
      af[i] = *(const f16x8*)(As + (wm + i * 16 + mrow) * 32 + kq);
#pragma unroll
    for (int j = 0; j < 4; j++)
      bf[j] = *(const f16x8*)(Bs + (wn + j * 16 + mrow) * 32 + kq);
#pragma unroll
    for (int i = 0; i < 4; i++)
#pragma unroll
      for (int j = 0; j < 4; j++)
        acc[i][j] = __builtin_amdgcn_mfma_f32_16x16x32_f16(af[i], bf[j], acc[i][j], 0, 0, 0);
  }

  // epilogue: C/D layout col=lane&15, row=(lane>>4)*4+reg
  const int ccol = lane & 15;
  const int crow = (lane >> 4) * 4;
#pragma unroll
  for (int j = 0; j < 4; j++) {
    const int col = col0 + wn + j * 16 + ccol;
    float bv = BIAS ? bias[col] : 0.f;
#pragma unroll
    for (int i = 0; i < 4; i++) {
      float* Cp = C + (size_t)(row0 + wm + i * 16 + crow) * DIM + col;
#pragma unroll
      for (int r = 0; r < 4; r++) Cp[(size_t)r * DIM] = acc[i][j][r] + bv;
    }
  }
}

// ---------------------------------------------------------------------------
// K2: per-(row,head) inverse L2 norms of f_q and f_k. One block per f row.
// ---------------------------------------------------------------------------
__global__ void __launch_bounds__(256) norms_kernel(
    const float* __restrict__ f, float* __restrict__ rq, float* __restrict__ rk) {
  int row = blockIdx.x;  // 0..RQ+RK-1 (q rows then k rows of f)
  int t = threadIdx.x;
  float4 x = ((const float4*)(f + (size_t)row * DIM))[t];
  float s2 = x.x * x.x + x.y * x.y + x.z * x.z + x.w * x.w;
  s2 += __shfl_xor(s2, 1);
  s2 += __shfl_xor(s2, 2);
  s2 += __shfl_xor(s2, 4);
  s2 += __shfl_xor(s2, 8);
  if ((t & 15) == 0) {
    int h = t >> 4;
    float inv = rsqrtf(s2);
    if (row < RQ) rq[(size_t)row * NH + h] = inv;
    else          rk[(size_t)(row - RQ) * NH + h] = inv;
  }
}

// ---------------------------------------------------------------------------
// K3: per-(b,h) S = sum_m (f_k[m]/kn[m]) outer f_v[m]  (64x64).
// ---------------------------------------------------------------------------
__global__ void __launch_bounds__(256) s_kernel(
    const float* __restrict__ f, const float* __restrict__ rk,
    float* __restrict__ S) {
  const int bh = blockIdx.x;
  const int b = bh >> 4, h = bh & 15;
  const int mbase = blockIdx.y * 512;
  const int t = threadIdx.x;
  __shared__ float ks[32][68];
  __shared__ float vs[32][68];
  const int lm   = t >> 3;
  const int lseg = (t & 7) * 8;
  const int d1 = (t & 15) * 4;
  const int d2 = (t >> 4) * 4;
  float acc[4][4] = {{0.f}};
  const float* fk_base = f + ((size_t)RQ + (size_t)b * SEQK) * DIM + h * DH;
  const float* fv_base = f + ((size_t)RQ + RK + (size_t)b * SEQK) * DIM + h * DH;

  for (int sub = 0; sub < 16; ++sub) {
    const int m = mbase + sub * 32 + lm;
    const float scale = rk[(size_t)(b * SEQK + m) * NH + h];
    const float* kr = fk_base + (size_t)m * DIM + lseg;
    const float* vr = fv_base + (size_t)m * DIM + lseg;
    float4 k0 = *(const float4*)kr;
    float4 k1 = *(const float4*)(kr + 4);
    float4 v0 = *(const float4*)vr;
    float4 v1 = *(const float4*)(vr + 4);
    __syncthreads();
    ks[lm][lseg + 0] = k0.x * scale; ks[lm][lseg + 1] = k0.y * scale;
    ks[lm][lseg + 2] = k0.z * scale; ks[lm][lseg + 3] = k0.w * scale;
    ks[lm][lseg + 4] = k1.x * scale; ks[lm][lseg + 5] = k1.y * scale;
    ks[lm][lseg + 6] = k1.z * scale; ks[lm][lseg + 7] = k1.w * scale;
    *(float4*)&vs[lm][lseg]     = v0;
    *(float4*)&vs[lm][lseg + 4] = v1;
    __syncthreads();
#pragma unroll
    for (int mm = 0; mm < 32; ++mm) {
      float4 kk = *(const float4*)&ks[mm][d1];
      float4 vv = *(const float4*)&vs[mm][d2];
      acc[0][0] = fmaf(kk.x, vv.x, acc[0][0]);
      acc[0][1] = fmaf(kk.x, vv.y, acc[0][1]);
      acc[0][2] = fmaf(kk.x, vv.z, acc[0][2]);
      acc[0][3] = fmaf(kk.x, vv.w, acc[0][3]);
      acc[1][0] = fmaf(kk.y, vv.x, acc[1][0]);
      acc[1][1] = fmaf(kk.y, vv.y, acc[1][1]);
      acc[1][2] = fmaf(kk.y, vv.z, acc[1][2]);
      acc[1][3] = fmaf(kk.y, vv.w, acc[1][3]);
      acc[2][0] = fmaf(kk.z, vv.x, acc[2][0]);
      acc[2][1] = fmaf(kk.z, vv.y, acc[2][1]);
      acc[2][2] = fmaf(kk.z, vv.z, acc[2][2]);
      acc[2][3] = fmaf(kk.z, vv.w, acc[2][3]);
      acc[3][0] = fmaf(kk.w, vv.x, acc[3][0]);
      acc[3][1] = fmaf(kk.w, vv.y, acc[3][1]);
      acc[3][2] = fmaf(kk.w, vv.z, acc[3][2]);
      acc[3][3] = fmaf(kk.w, vv.w, acc[3][3]);
    }
  }
  float* Sp = S + (size_t)bh * DH * DH;
#pragma unroll
  for (int i = 0; i < 4; i++)
#pragma unroll
    for (int j = 0; j < 4; j++)
      atomicAdd(&Sp[(d1 + i) * DH + (d2 + j)], acc[i][j]);
}

// ---------------------------------------------------------------------------
// K4: ao[b, n, h*64+d2] = ((f_q[b,n,h,:] @ S[b,h]) * rq[b,n,h]) as fp16
// ---------------------------------------------------------------------------
__global__ void __launch_bounds__(256) outhead_kernel(
    const float* __restrict__ f, const float* __restrict__ S,
    const float* __restrict__ rq, f16* __restrict__ ao) {
  const int bh = blockIdx.x;
  const int b = bh >> 4, h = bh & 15;
  const int nbase = blockIdx.y * 64;
  const int t = threadIdx.x;
  __shared__ float Sl[64][68];
  __shared__ float Ql[64][68];
  {
    const int r = t >> 2;
    const int seg = (t & 3) * 16;
    const float* Sp = S + (size_t)bh * DH * DH + r * DH + seg;
    const float* Qp = f + ((size_t)b * SEQQ + nbase + r) * DIM + h * DH + seg;
#pragma unroll
    for (int c = 0; c < 4; c++) {
      *(float4*)&Sl[r][seg + 4 * c] = ((const float4*)Sp)[c];
      *(float4*)&Ql[r][seg + 4 * c] = ((const float4*)Qp)[c];
    }
  }
  __syncthreads();
  const int d2 = (t & 15) * 4;
  const int g  = t >> 4;
#pragma unroll
  for (int i = 0; i < 4; ++i) {
    const int n = i * 16 + g;
    float4 acc = {0.f, 0.f, 0.f, 0.f};
#pragma unroll 8
    for (int d1 = 0; d1 < 64; ++d1) {
      float qv = Ql[n][d1];
      float4 sv = *(const float4*)&Sl[d1][d2];
      acc.x = fmaf(qv, sv.x, acc.x);
      acc.y = fmaf(qv, sv.y, acc.y);
      acc.z = fmaf(qv, sv.z, acc.z);
      acc.w = fmaf(qv, sv.w, acc.w);
    }
    const float r = rq[((size_t)b * SEQQ + nbase + n) * NH + h];
    union { f16 h4[4]; uint2 u; } o;
    o.h4[0] = (f16)(acc.x * r);
    o.h4[1] = (f16)(acc.y * r);
    o.h4[2] = (f16)(acc.z * r);
    o.h4[3] = (f16)(acc.w * r);
    *(uint2*)(ao + ((size_t)b * SEQQ + nbase + n) * DIM + h * DH + d2) = o.u;
  }
}

// ---------------------------------------------------------------------------
extern "C" void kernel_launch(void* const* d_in, const int* in_sizes, int n_in,
                              void* d_out, int out_size, void* d_ws, size_t ws_size,
                              hipStream_t stream) {
  const float* q     = (const float*)d_in[0];
  const float* k     = (const float*)d_in[1];
  const float* v     = (const float*)d_in[2];
  const float* gamma = (const float*)d_in[3];
  const float* beta  = (const float*)d_in[4];
  const float* W_in  = (const float*)d_in[5];
  const float* W_out = (const float*)d_in[6];
  const float* b_out = (const float*)d_in[7];
  float* out = (float*)d_out;

  // workspace layout
  char* w = (char*)d_ws;
  float* f      = (float*)w;                                   // 80 MB
  f16*   a_h    = (f16*)(w + (size_t)RTOT * DIM * 4);          // 40 MB
  f16*   wt_in  = a_h + (size_t)RTOT * DIM;                    // 2 MB
  f16*   wt_out = wt_in + (size_t)DIM * DIM;                   // 2 MB
  float* rqb    = (float*)(wt_out + (size_t)DIM * DIM);        // 256 KB
  float* rkb    = rqb + (size_t)RQ * NH;                       // 512 KB
  float* S      = rkb + (size_t)RK * NH;                       // 1 MB
  f16*   ao     = a_h;  // alias: a_h dead after projection GEMM

  hipMemsetAsync(S, 0, (size_t)BATCH * NH * DH * DH * sizeof(float), stream);

  ln_to_f16<<<RTOT, 256, 0, stream>>>(q, k, v, gamma, beta, a_h);
  transpose_f16<<<dim3(DIM / 32, DIM / 32, 2), 256, 0, stream>>>(
      W_in, W_out, wt_in, wt_out);

  // f = LN(t) @ W_in for all 20480 rows in one launch
  mfma_gemm<false><<<dim3(RTOT / 128, DIM / 128), 256, 0, stream>>>(
      a_h, wt_in, f, nullptr);

  norms_kernel<<<RQ + RK, 256, 0, stream>>>(f, rqb, rkb);

  s_kernel<<<dim3(BATCH * NH, 4), 256, 0, stream>>>(f, rkb, S);

  outhead_kernel<<<dim3(BATCH * NH, SEQQ / 64), 256, 0, stream>>>(f, S, rqb, ao);

  // out = ao @ W_out + b_out
  mfma_gemm<true><<<dim3(RQ / 128, DIM / 128), 256, 0, stream>>>(
      ao, wt_out, out, b_out);
}

// Round 3
// 257.300 us; speedup vs baseline: 3.5557x; 1.1022x over previous
//
#include <hip/hip_runtime.h>

// Problem constants
constexpr int BATCH = 4;
constexpr int SEQQ  = 1024;
constexpr int SEQK  = 2048;
constexpr int DIM   = 1024;
constexpr int NH    = 16;
constexpr int DH    = 64;
constexpr int RQ    = BATCH * SEQQ;          // 4096 q rows
constexpr int RK    = BATCH * SEQK;          // 8192 k rows (== v rows)
constexpr int RTOT  = RQ + 2 * RK;           // 20480
constexpr int BH    = BATCH * NH;            // 64
constexpr float LN_EPS = 1e-5f;

typedef _Float16 f16;
typedef __attribute__((ext_vector_type(8))) _Float16 f16x8;
typedef __attribute__((ext_vector_type(4))) float f32x4;

__device__ __forceinline__ void async16(const void* g, void* l) {
  __builtin_amdgcn_global_load_lds(
      (const __attribute__((address_space(1))) void*)g,
      (__attribute__((address_space(3))) void*)l, 16, 0, 0);
}

// ---------------------------------------------------------------------------
// K0: fused LayerNorm -> fp16 for q,k,v rows. One block per row.
// ---------------------------------------------------------------------------
__global__ void __launch_bounds__(256) ln_to_f16(
    const float* __restrict__ q, const float* __restrict__ k,
    const float* __restrict__ v, const float* __restrict__ gamma,
    const float* __restrict__ beta, f16* __restrict__ a_h) {
  int row = blockIdx.x;
  const float* src;
  if (row < RQ)            src = q + (size_t)row * DIM;
  else if (row < RQ + RK)  src = k + (size_t)(row - RQ) * DIM;
  else                     src = v + (size_t)(row - RQ - RK) * DIM;
  int t = threadIdx.x;
  float4 x = ((const float4*)src)[t];
  float s  = x.x + x.y + x.z + x.w;
  float s2 = x.x * x.x + x.y * x.y + x.z * x.z + x.w * x.w;
  for (int off = 32; off; off >>= 1) {
    s  += __shfl_down(s, off);
    s2 += __shfl_down(s2, off);
  }
  __shared__ float ls[4], ls2[4];
  __shared__ float smu, srs;
  int wid = t >> 6;
  if ((t & 63) == 0) { ls[wid] = s; ls2[wid] = s2; }
  __syncthreads();
  if (t == 0) {
    float S1 = ls[0] + ls[1] + ls[2] + ls[3];
    float S2 = ls2[0] + ls2[1] + ls2[2] + ls2[3];
    float mu  = S1 / DIM;
    float var = S2 / DIM - mu * mu;
    smu = mu;
    srs = rsqrtf(var + LN_EPS);
  }
  __syncthreads();
  float mu = smu, rs = srs;
  float4 g = ((const float4*)gamma)[t];
  float4 b = ((const float4*)beta)[t];
  union { f16 h[4]; uint2 u; } o;
  o.h[0] = (f16)((x.x - mu) * rs * g.x + b.x);
  o.h[1] = (f16)((x.y - mu) * rs * g.y + b.y);
  o.h[2] = (f16)((x.z - mu) * rs * g.z + b.z);
  o.h[3] = (f16)((x.w - mu) * rs * g.w + b.w);
  ((uint2*)(a_h + (size_t)row * DIM))[t] = o.u;
}

// ---------------------------------------------------------------------------
// K0b: transpose + fp16 convert of W_in and W_out (1024x1024 each).
// ---------------------------------------------------------------------------
__global__ void __launch_bounds__(256) transpose_f16(
    const float* __restrict__ W0, const float* __restrict__ W1,
    f16* __restrict__ T0, f16* __restrict__ T1) {
  const float* W = blockIdx.z ? W1 : W0;
  f16* T = blockIdx.z ? T1 : T0;
  __shared__ float tile[32][33];
  int tx = threadIdx.x & 31, ty = threadIdx.x >> 5;
  int k0 = blockIdx.x * 32, n0 = blockIdx.y * 32;
#pragma unroll
  for (int i = 0; i < 4; i++)
    tile[ty + 8 * i][tx] = W[(size_t)(k0 + ty + 8 * i) * DIM + n0 + tx];
  __syncthreads();
#pragma unroll
  for (int i = 0; i < 4; i++)
    T[(size_t)(n0 + ty + 8 * i) * DIM + k0 + tx] = (f16)tile[tx][ty + 8 * i];
}

// ---------------------------------------------------------------------------
// MFMA fp16 GEMM, C[M x 1024] = A[M x 1024] * Bt^T, Bt N-major [1024][1024].
// 128x128 tile, BK=64 as two BK=32 sub-buffers (one barrier pair per 64-K).
// 4 waves, each a 64x64 quadrant = 4x4 of 16x16x32 MFMAs.
// NORMS: fused per-(row,head) rsqrt(sum x^2) of the fp32 accumulators —
// each wave's 64-col quadrant is exactly one head.
// ---------------------------------------------------------------------------
template <bool OUT_F16, bool NORMS, bool BIAS>
__global__ void __launch_bounds__(256) mfma_gemm(
    const f16* __restrict__ A, const f16* __restrict__ Bt,
    void* __restrict__ Cout, const float* __restrict__ bias,
    float* __restrict__ rq, float* __restrict__ rk) {
  __shared__ f16 As[2][128 * 32];
  __shared__ f16 Bs[2][128 * 32];
  const int t = threadIdx.x;
  const int wid = t >> 6;
  const int lane = t & 63;
  const int row0 = blockIdx.x * 128;
  const int col0 = blockIdx.y * 128;
  const int wm = (wid >> 1) * 64;
  const int wn = (wid & 1) * 64;

  // staging: wave w stages rows [32w,32w+32) of A and Bt per sub-buffer.
  const f16* gA = A + (size_t)(row0 + 32 * wid + (lane >> 2)) * DIM + (lane & 3) * 8;
  const f16* gB = Bt + (size_t)(col0 + 32 * wid + (lane >> 2)) * DIM + (lane & 3) * 8;
  f16* lA0 = As[0] + 32 * wid * 32;
  f16* lA1 = As[1] + 32 * wid * 32;
  f16* lB0 = Bs[0] + 32 * wid * 32;
  f16* lB1 = Bs[1] + 32 * wid * 32;

  f32x4 acc[4][4];
#pragma unroll
  for (int i = 0; i < 4; i++)
#pragma unroll
    for (int j = 0; j < 4; j++) acc[i][j] = (f32x4){0.f, 0.f, 0.f, 0.f};

  const int mrow = lane & 15;
  const int kq   = (lane >> 4) * 8;

  for (int kt = 0; kt < DIM / 64; ++kt) {
    if (kt) __syncthreads();
    const int ko = kt * 64;
    async16(gA + ko,                lA0);
    async16(gA + ko + 16 * DIM,     lA0 + 512);
    async16(gB + ko,                lB0);
    async16(gB + ko + 16 * DIM,     lB0 + 512);
    async16(gA + ko + 32,           lA1);
    async16(gA + ko + 32 + 16 * DIM, lA1 + 512);
    async16(gB + ko + 32,           lB1);
    async16(gB + ko + 32 + 16 * DIM, lB1 + 512);
    __syncthreads();

#pragma unroll
    for (int h = 0; h < 2; ++h) {
      f16x8 af[4], bf[4];
#pragma unroll
      for (int i = 0; i < 4; i++)
        af[i] = *(const f16x8*)(As[h] + (wm + i * 16 + mrow) * 32 + kq);
#pragma unroll
      for (int j = 0; j < 4; j++)
        bf[j] = *(const f16x8*)(Bs[h] + (wn + j * 16 + mrow) * 32 + kq);
#pragma unroll
      for (int i = 0; i < 4; i++)
#pragma unroll
        for (int j = 0; j < 4; j++)
          acc[i][j] = __builtin_amdgcn_mfma_f32_16x16x32_f16(af[i], bf[j], acc[i][j], 0, 0, 0);
    }
  }

  // epilogue: C/D layout col=lane&15, row=(lane>>4)*4+reg
  const int ccol = lane & 15;
  const int crow = (lane >> 4) * 4;
  if (OUT_F16) {
    f16* C = (f16*)Cout;
#pragma unroll
    for (int j = 0; j < 4; j++) {
      const int col = col0 + wn + j * 16 + ccol;
#pragma unroll
      for (int i = 0; i < 4; i++) {
        f16* Cp = C + (size_t)(row0 + wm + i * 16 + crow) * DIM + col;
#pragma unroll
        for (int r = 0; r < 4; r++) Cp[(size_t)r * DIM] = (f16)acc[i][j][r];
      }
    }
  } else {
    float* C = (float*)Cout;
#pragma unroll
    for (int j = 0; j < 4; j++) {
      const int col = col0 + wn + j * 16 + ccol;
      float bv = BIAS ? bias[col] : 0.f;
#pragma unroll
      for (int i = 0; i < 4; i++) {
        float* Cp = C + (size_t)(row0 + wm + i * 16 + crow) * DIM + col;
#pragma unroll
        for (int r = 0; r < 4; r++) Cp[(size_t)r * DIM] = acc[i][j][r] + bv;
      }
    }
  }

  if (NORMS) {
    // per-row sum of squares over this wave's 64 cols (= one head)
    float sums[4][4];
#pragma unroll
    for (int i = 0; i < 4; i++)
#pragma unroll
      for (int r = 0; r < 4; r++) {
        float s = 0.f;
#pragma unroll
        for (int j = 0; j < 4; j++) s += acc[i][j][r] * acc[i][j][r];
        sums[i][r] = s;
      }
#pragma unroll
    for (int off = 1; off < 16; off <<= 1)
#pragma unroll
      for (int i = 0; i < 4; i++)
#pragma unroll
        for (int r = 0; r < 4; r++)
          sums[i][r] += __shfl_xor(sums[i][r], off);
    if ((lane & 15) == 0) {
      const int head = (col0 + wn) >> 6;
#pragma unroll
      for (int i = 0; i < 4; i++)
#pragma unroll
        for (int r = 0; r < 4; r++) {
          const int row = row0 + wm + i * 16 + crow + r;
          const float inv = rsqrtf(sums[i][r]);
          if (row < RQ)            rq[(size_t)row * NH + head] = inv;
          else if (row < RQ + RK)  rk[(size_t)(row - RQ) * NH + head] = inv;
          // v rows: norm unused
        }
    }
  }
}

// ---------------------------------------------------------------------------
// K3: per-(y,b,h) partial S = sum over 512 m of (f_k[m]*rk[m]) outer f_v[m].
// Non-atomic: 4 partial slices, summed by outhead.
// ---------------------------------------------------------------------------
__global__ void __launch_bounds__(256) s_kernel(
    const f16* __restrict__ f, const float* __restrict__ rk,
    float* __restrict__ S4) {
  const int bh = blockIdx.x;
  const int b = bh >> 4, h = bh & 15;
  const int mbase = blockIdx.y * 512;
  const int t = threadIdx.x;
  __shared__ float ks[32][68];
  __shared__ float vs[32][68];
  const int lm   = t >> 3;
  const int lseg = (t & 7) * 8;
  const int d1 = (t & 15) * 4;
  const int d2 = (t >> 4) * 4;
  float acc[4][4] = {{0.f}};
  const f16* fk_base = f + ((size_t)RQ + (size_t)b * SEQK) * DIM + h * DH;
  const f16* fv_base = f + ((size_t)RQ + RK + (size_t)b * SEQK) * DIM + h * DH;

  for (int sub = 0; sub < 16; ++sub) {
    const int m = mbase + sub * 32 + lm;
    const float scale = rk[(size_t)(b * SEQK + m) * NH + h];
    f16x8 kv = *(const f16x8*)(fk_base + (size_t)m * DIM + lseg);
    f16x8 vv = *(const f16x8*)(fv_base + (size_t)m * DIM + lseg);
    __syncthreads();
#pragma unroll
    for (int e = 0; e < 8; e++) {
      ks[lm][lseg + e] = (float)kv[e] * scale;
      vs[lm][lseg + e] = (float)vv[e];
    }
    __syncthreads();
#pragma unroll
    for (int mm = 0; mm < 32; ++mm) {
      float4 kk = *(const float4*)&ks[mm][d1];
      float4 vv2 = *(const float4*)&vs[mm][d2];
      acc[0][0] = fmaf(kk.x, vv2.x, acc[0][0]);
      acc[0][1] = fmaf(kk.x, vv2.y, acc[0][1]);
      acc[0][2] = fmaf(kk.x, vv2.z, acc[0][2]);
      acc[0][3] = fmaf(kk.x, vv2.w, acc[0][3]);
      acc[1][0] = fmaf(kk.y, vv2.x, acc[1][0]);
      acc[1][1] = fmaf(kk.y, vv2.y, acc[1][1]);
      acc[1][2] = fmaf(kk.y, vv2.z, acc[1][2]);
      acc[1][3] = fmaf(kk.y, vv2.w, acc[1][3]);
      acc[2][0] = fmaf(kk.z, vv2.x, acc[2][0]);
      acc[2][1] = fmaf(kk.z, vv2.y, acc[2][1]);
      acc[2][2] = fmaf(kk.z, vv2.z, acc[2][2]);
      acc[2][3] = fmaf(kk.z, vv2.w, acc[2][3]);
      acc[3][0] = fmaf(kk.w, vv2.x, acc[3][0]);
      acc[3][1] = fmaf(kk.w, vv2.y, acc[3][1]);
      acc[3][2] = fmaf(kk.w, vv2.z, acc[3][2]);
      acc[3][3] = fmaf(kk.w, vv2.w, acc[3][3]);
    }
  }
  float* Sp = S4 + ((size_t)blockIdx.y * BH + bh) * DH * DH;
#pragma unroll
  for (int i = 0; i < 4; i++)
#pragma unroll
    for (int j = 0; j < 4; j++)
      Sp[(d1 + i) * DH + (d2 + j)] = acc[i][j];
}

// ---------------------------------------------------------------------------
// K4: ao[b, n, h*64+d2] = ((f_q[b,n,h,:] @ S[b,h]) * rq[b,n,h]) as fp16.
// S[b,h] = sum of the 4 partial slices (summed during LDS staging).
// ---------------------------------------------------------------------------
__global__ void __launch_bounds__(256) outhead_kernel(
    const f16* __restrict__ f, const float* __restrict__ S4,
    const float* __restrict__ rq, f16* __restrict__ ao) {
  const int bh = blockIdx.x;
  const int b = bh >> 4, h = bh & 15;
  const int nbase = blockIdx.y * 64;
  const int t = threadIdx.x;
  __shared__ float Sl[64][68];
  __shared__ float Ql[64][68];
  {
    const int r = t >> 2;
    const int seg = (t & 3) * 16;
    const float* Sp = S4 + (size_t)bh * DH * DH + r * DH + seg;
    constexpr size_t STR = (size_t)BH * DH * DH;
#pragma unroll
    for (int c = 0; c < 4; c++) {
      float4 s0 = ((const float4*)Sp)[c];
      float4 s1 = ((const float4*)(Sp + STR))[c];
      float4 s2 = ((const float4*)(Sp + 2 * STR))[c];
      float4 s3 = ((const float4*)(Sp + 3 * STR))[c];
      float4 s;
      s.x = s0.x + s1.x + s2.x + s3.x;
      s.y = s0.y + s1.y + s2.y + s3.y;
      s.z = s0.z + s1.z + s2.z + s3.z;
      s.w = s0.w + s1.w + s2.w + s3.w;
      *(float4*)&Sl[r][seg + 4 * c] = s;
    }
    const f16* Qp = f + ((size_t)b * SEQQ + nbase + r) * DIM + h * DH + seg;
    f16x8 q0 = *(const f16x8*)Qp;
    f16x8 q1 = *(const f16x8*)(Qp + 8);
#pragma unroll
    for (int e = 0; e < 8; e++) {
      Ql[r][seg + e]     = (float)q0[e];
      Ql[r][seg + 8 + e] = (float)q1[e];
    }
  }
  __syncthreads();
  const int d2 = (t & 15) * 4;
  const int g  = t >> 4;
#pragma unroll
  for (int i = 0; i < 4; ++i) {
    const int n = i * 16 + g;
    float4 acc = {0.f, 0.f, 0.f, 0.f};
#pragma unroll 8
    for (int d1 = 0; d1 < 64; ++d1) {
      float qv = Ql[n][d1];
      float4 sv = *(const float4*)&Sl[d1][d2];
      acc.x = fmaf(qv, sv.x, acc.x);
      acc.y = fmaf(qv, sv.y, acc.y);
      acc.z = fmaf(qv, sv.z, acc.z);
      acc.w = fmaf(qv, sv.w, acc.w);
    }
    const float r = rq[((size_t)b * SEQQ + nbase + n) * NH + h];
    union { f16 h4[4]; uint2 u; } o;
    o.h4[0] = (f16)(acc.x * r);
    o.h4[1] = (f16)(acc.y * r);
    o.h4[2] = (f16)(acc.z * r);
    o.h4[3] = (f16)(acc.w * r);
    *(uint2*)(ao + ((size_t)b * SEQQ + nbase + n) * DIM + h * DH + d2) = o.u;
  }
}

// ---------------------------------------------------------------------------
extern "C" void kernel_launch(void* const* d_in, const int* in_sizes, int n_in,
                              void* d_out, int out_size, void* d_ws, size_t ws_size,
                              hipStream_t stream) {
  const float* q     = (const float*)d_in[0];
  const float* k     = (const float*)d_in[1];
  const float* v     = (const float*)d_in[2];
  const float* gamma = (const float*)d_in[3];
  const float* beta  = (const float*)d_in[4];
  const float* W_in  = (const float*)d_in[5];
  const float* W_out = (const float*)d_in[6];
  const float* b_out = (const float*)d_in[7];
  float* out = (float*)d_out;

  // workspace layout
  char* w = (char*)d_ws;
  f16*   f      = (f16*)w;                                     // 40 MB
  f16*   a_h    = f + (size_t)RTOT * DIM;                      // 40 MB
  f16*   wt_in  = a_h + (size_t)RTOT * DIM;                    // 2 MB
  f16*   wt_out = wt_in + (size_t)DIM * DIM;                   // 2 MB
  float* rqb    = (float*)(wt_out + (size_t)DIM * DIM);        // 256 KB
  float* rkb    = rqb + (size_t)RQ * NH;                       // 512 KB
  float* S4     = rkb + (size_t)RK * NH;                       // 4 MB
  f16*   ao     = a_h;  // alias: a_h dead after projection GEMM

  ln_to_f16<<<RTOT, 256, 0, stream>>>(q, k, v, gamma, beta, a_h);
  transpose_f16<<<dim3(DIM / 32, DIM / 32, 2), 256, 0, stream>>>(
      W_in, W_out, wt_in, wt_out);

  // f = LN(t) @ W_in for all 20480 rows; fused per-head inverse norms
  mfma_gemm<true, true, false><<<dim3(RTOT / 128, DIM / 128), 256, 0, stream>>>(
      a_h, wt_in, f, nullptr, rqb, rkb);

  s_kernel<<<dim3(BH, 4), 256, 0, stream>>>(f, rkb, S4);

  outhead_kernel<<<dim3(BH, SEQQ / 64), 256, 0, stream>>>(f, S4, rqb, ao);

  // out = ao @ W_out + b_out
  mfma_gemm<false, false, true><<<dim3(RQ / 128, DIM / 128), 256, 0, stream>>>(
      ao, wt_out, out, b_out, nullptr, nullptr);
}

// Round 4
// 244.505 us; speedup vs baseline: 3.7418x; 1.0523x over previous
//
#include <hip/hip_runtime.h>

// Problem constants
constexpr int BATCH = 4;
constexpr int SEQQ  = 1024;
constexpr int SEQK  = 2048;
constexpr int DIM   = 1024;
constexpr int NH    = 16;
constexpr int DH    = 64;
constexpr int RQ    = BATCH * SEQQ;          // 4096 q rows
constexpr int RK    = BATCH * SEQK;          // 8192 k rows (== v rows)
constexpr int RTOT  = RQ + 2 * RK;           // 20480
constexpr int BH    = BATCH * NH;            // 64
constexpr int NSLC  = 8;                     // s_kernel K-slices
constexpr float LN_EPS = 1e-5f;

typedef _Float16 f16;
typedef __attribute__((ext_vector_type(8))) _Float16 f16x8;
typedef __attribute__((ext_vector_type(4))) float f32x4;

__device__ __forceinline__ void async16(const void* g, void* l) {
  __builtin_amdgcn_global_load_lds(
      (const __attribute__((address_space(1))) void*)g,
      (__attribute__((address_space(3))) void*)l, 16, 0, 0);
}

// ---------------------------------------------------------------------------
// K0: fused LayerNorm -> fp16. One wave per row (no LDS, no barriers).
// ---------------------------------------------------------------------------
__global__ void __launch_bounds__(256) ln_to_f16(
    const float* __restrict__ q, const float* __restrict__ k,
    const float* __restrict__ v, const float* __restrict__ gamma,
    const float* __restrict__ beta, f16* __restrict__ a_h) {
  const int row = blockIdx.x * 4 + (threadIdx.x >> 6);
  const int lane = threadIdx.x & 63;
  const float* src;
  if (row < RQ)            src = q + (size_t)row * DIM;
  else if (row < RQ + RK)  src = k + (size_t)(row - RQ) * DIM;
  else                     src = v + (size_t)(row - RQ - RK) * DIM;
  float4 x[4];
  float s = 0.f, s2 = 0.f;
#pragma unroll
  for (int c = 0; c < 4; c++) {
    x[c] = ((const float4*)src)[c * 64 + lane];
    s  += x[c].x + x[c].y + x[c].z + x[c].w;
    s2 += x[c].x * x[c].x + x[c].y * x[c].y + x[c].z * x[c].z + x[c].w * x[c].w;
  }
#pragma unroll
  for (int off = 1; off < 64; off <<= 1) {
    s  += __shfl_xor(s, off);
    s2 += __shfl_xor(s2, off);
  }
  const float mu = s / DIM;
  const float rs = rsqrtf(s2 / DIM - mu * mu + LN_EPS);
#pragma unroll
  for (int c = 0; c < 4; c++) {
    float4 g = ((const float4*)gamma)[c * 64 + lane];
    float4 b = ((const float4*)beta)[c * 64 + lane];
    union { f16 h[4]; uint2 u; } o;
    o.h[0] = (f16)((x[c].x - mu) * rs * g.x + b.x);
    o.h[1] = (f16)((x[c].y - mu) * rs * g.y + b.y);
    o.h[2] = (f16)((x[c].z - mu) * rs * g.z + b.z);
    o.h[3] = (f16)((x[c].w - mu) * rs * g.w + b.w);
    ((uint2*)(a_h + (size_t)row * DIM))[c * 64 + lane] = o.u;
  }
}

// ---------------------------------------------------------------------------
// K0b: transpose + fp16 convert of W_in and W_out (1024x1024 each).
// ---------------------------------------------------------------------------
__global__ void __launch_bounds__(256) transpose_f16(
    const float* __restrict__ W0, const float* __restrict__ W1,
    f16* __restrict__ T0, f16* __restrict__ T1) {
  const float* W = blockIdx.z ? W1 : W0;
  f16* T = blockIdx.z ? T1 : T0;
  __shared__ float tile[32][33];
  int tx = threadIdx.x & 31, ty = threadIdx.x >> 5;
  int k0 = blockIdx.x * 32, n0 = blockIdx.y * 32;
#pragma unroll
  for (int i = 0; i < 4; i++)
    tile[ty + 8 * i][tx] = W[(size_t)(k0 + ty + 8 * i) * DIM + n0 + tx];
  __syncthreads();
#pragma unroll
  for (int i = 0; i < 4; i++)
    T[(size_t)(n0 + ty + 8 * i) * DIM + k0 + tx] = (f16)tile[tx][ty + 8 * i];
}

// ---------------------------------------------------------------------------
// MFMA fp16 GEMM, C[M x 1024] = A[M x 1024] * Bt^T, Bt N-major [1024][1024].
// MT x 128 tile, BK=64 as two BK=32 sub-buffers, one barrier pair per 64-K.
// LDS chunk rotation swizzle: physical 16B chunk p = (q + (row>>1)) & 3 —
// makes fragment ds_read_b128 conflict-free (was 8-way, +4 cyc/read).
// MT=128: 4 waves as 2x2 quadrants of 64x64 (4x4 MFMA grid).
// MT=64:  4 waves as 1x4 slices of 64x32 (4x2 MFMA grid) — 2x blocks for
//         the small out-GEMM (occupancy > compute:load ratio there).
// NORMS (MT=128 only): fused per-(row,head) rsqrt(sum x^2) — each wave's
// 64-col quadrant is exactly one head.
// ---------------------------------------------------------------------------
template <int MT, bool OUT_F16, bool NORMS, bool BIAS>
__global__ void __launch_bounds__(256) mfma_gemm(
    const f16* __restrict__ A, const f16* __restrict__ Bt,
    void* __restrict__ Cout, const float* __restrict__ bias,
    float* __restrict__ rq, float* __restrict__ rk) {
  constexpr int JT = (MT == 128) ? 4 : 2;
  __shared__ f16 As[2][MT * 32];
  __shared__ f16 Bs[2][128 * 32];
  const int t = threadIdx.x;
  const int wid = t >> 6;
  const int lane = t & 63;
  const int row0 = blockIdx.x * MT;
  const int col0 = blockIdx.y * 128;
  const int wm = (MT == 128) ? (wid >> 1) * 64 : 0;
  const int wn = (MT == 128) ? (wid & 1) * 64 : wid * 32;

  // ---- staging pointers (with chunk-rotation swizzle on the fetch column)
  // B: each wave stages 32 rows of Bt per sub-buffer (2 instrs).
  const int rB = 32 * wid + (lane >> 2);
  const int qB = ((lane & 3) - ((rB >> 1) & 3)) & 3;
  const f16* gB = Bt + (size_t)(col0 + rB) * DIM + qB * 8;
  f16* lB0 = Bs[0] + 32 * wid * 32;
  f16* lB1 = Bs[1] + 32 * wid * 32;
  // A: MT=128 -> 32 rows/wave (2 instrs); MT=64 -> 16 rows/wave (1 instr).
  const int rA = (MT == 128 ? 32 : 16) * wid + (lane >> 2);
  const int qA = ((lane & 3) - ((rA >> 1) & 3)) & 3;
  const f16* gA = A + (size_t)(row0 + rA) * DIM + qA * 8;
  f16* lA0 = As[0] + (MT == 128 ? 32 : 16) * wid * 32;
  f16* lA1 = As[1] + (MT == 128 ? 32 : 16) * wid * 32;

  f32x4 acc[4][JT];
#pragma unroll
  for (int i = 0; i < 4; i++)
#pragma unroll
    for (int j = 0; j < JT; j++) acc[i][j] = (f32x4){0.f, 0.f, 0.f, 0.f};

  const int mrow = lane & 15;
  // physical chunk for this lane's logical k-quad (row-dependence reduces to
  // (mrow>>1)&3, identical for all row tiles since wm,16i are ≡0 mod 8)
  const int kq_p = (((lane >> 4) + ((lane >> 1) & 3)) & 3) * 8;

  for (int kt = 0; kt < DIM / 64; ++kt) {
    if (kt) __syncthreads();
    const int ko = kt * 64;
    async16(gA + ko,      lA0);
    if (MT == 128) async16(gA + ko + 16 * DIM, lA0 + 512);
    async16(gB + ko,      lB0);
    async16(gB + ko + 16 * DIM, lB0 + 512);
    async16(gA + ko + 32, lA1);
    if (MT == 128) async16(gA + ko + 32 + 16 * DIM, lA1 + 512);
    async16(gB + ko + 32, lB1);
    async16(gB + ko + 32 + 16 * DIM, lB1 + 512);
    __syncthreads();

#pragma unroll
    for (int h = 0; h < 2; ++h) {
      f16x8 af[4], bf[JT];
#pragma unroll
      for (int i = 0; i < 4; i++)
        af[i] = *(const f16x8*)(As[h] + (wm + i * 16 + mrow) * 32 + kq_p);
#pragma unroll
      for (int j = 0; j < JT; j++)
        bf[j] = *(const f16x8*)(Bs[h] + (wn + j * 16 + mrow) * 32 + kq_p);
#pragma unroll
      for (int i = 0; i < 4; i++)
#pragma unroll
        for (int j = 0; j < JT; j++)
          acc[i][j] = __builtin_amdgcn_mfma_f32_16x16x32_f16(af[i], bf[j], acc[i][j], 0, 0, 0);
    }
  }

  // epilogue: C/D layout col=lane&15, row=(lane>>4)*4+reg
  const int ccol = lane & 15;
  const int crow = (lane >> 4) * 4;
  if (OUT_F16) {
    f16* C = (f16*)Cout;
#pragma unroll
    for (int j = 0; j < JT; j++) {
      const int col = col0 + wn + j * 16 + ccol;
#pragma unroll
      for (int i = 0; i < 4; i++) {
        f16* Cp = C + (size_t)(row0 + wm + i * 16 + crow) * DIM + col;
#pragma unroll
        for (int r = 0; r < 4; r++) Cp[(size_t)r * DIM] = (f16)acc[i][j][r];
      }
    }
  } else {
    float* C = (float*)Cout;
#pragma unroll
    for (int j = 0; j < JT; j++) {
      const int col = col0 + wn + j * 16 + ccol;
      float bv = BIAS ? bias[col] : 0.f;
#pragma unroll
      for (int i = 0; i < 4; i++) {
        float* Cp = C + (size_t)(row0 + wm + i * 16 + crow) * DIM + col;
#pragma unroll
        for (int r = 0; r < 4; r++) Cp[(size_t)r * DIM] = acc[i][j][r] + bv;
      }
    }
  }

  if (NORMS && MT == 128) {
    float sums[4][4];
#pragma unroll
    for (int i = 0; i < 4; i++)
#pragma unroll
      for (int r = 0; r < 4; r++) {
        float s = 0.f;
#pragma unroll
        for (int j = 0; j < JT; j++) s += acc[i][j][r] * acc[i][j][r];
        sums[i][r] = s;
      }
#pragma unroll
    for (int off = 1; off < 16; off <<= 1)
#pragma unroll
      for (int i = 0; i < 4; i++)
#pragma unroll
        for (int r = 0; r < 4; r++)
          sums[i][r] += __shfl_xor(sums[i][r], off);
    if ((lane & 15) == 0) {
      const int head = (col0 + wn) >> 6;
#pragma unroll
      for (int i = 0; i < 4; i++)
#pragma unroll
        for (int r = 0; r < 4; r++) {
          const int row = row0 + wm + i * 16 + crow + r;
          const float inv = rsqrtf(sums[i][r]);
          if (row < RQ)            rq[(size_t)row * NH + head] = inv;
          else if (row < RQ + RK)  rk[(size_t)(row - RQ) * NH + head] = inv;
        }
    }
  }
}

// ---------------------------------------------------------------------------
// K3: per-(y,b,h) partial S = sum over 256 m of (f_k[m]*rk[m]) outer f_v[m].
// 8 slices, non-atomic; register prefetch of next sub-tile hides HBM latency.
// ---------------------------------------------------------------------------
__global__ void __launch_bounds__(256) s_kernel(
    const f16* __restrict__ f, const float* __restrict__ rk,
    float* __restrict__ S4) {
  const int bh = blockIdx.x;
  const int b = bh >> 4, h = bh & 15;
  const int mbase = blockIdx.y * (SEQK / NSLC);
  const int t = threadIdx.x;
  __shared__ float ks[32][68];
  __shared__ float vs[32][68];
  const int lm   = t >> 3;
  const int lseg = (t & 7) * 8;
  const int d1 = (t & 15) * 4;
  const int d2 = (t >> 4) * 4;
  float acc[4][4] = {{0.f}};
  const f16* fk_base = f + ((size_t)RQ + (size_t)b * SEQK) * DIM + h * DH;
  const f16* fv_base = f + ((size_t)RQ + RK + (size_t)b * SEQK) * DIM + h * DH;

  int m = mbase + lm;
  f16x8 kv = *(const f16x8*)(fk_base + (size_t)m * DIM + lseg);
  f16x8 vv = *(const f16x8*)(fv_base + (size_t)m * DIM + lseg);
  float sc = rk[(size_t)(b * SEQK + m) * NH + h];

  constexpr int SUBS = SEQK / NSLC / 32;  // 8
  for (int sub = 0; sub < SUBS; ++sub) {
    __syncthreads();
#pragma unroll
    for (int e = 0; e < 8; e++) {
      ks[lm][lseg + e] = (float)kv[e] * sc;
      vs[lm][lseg + e] = (float)vv[e];
    }
    __syncthreads();
    if (sub + 1 < SUBS) {
      m = mbase + (sub + 1) * 32 + lm;
      kv = *(const f16x8*)(fk_base + (size_t)m * DIM + lseg);
      vv = *(const f16x8*)(fv_base + (size_t)m * DIM + lseg);
      sc = rk[(size_t)(b * SEQK + m) * NH + h];
    }
#pragma unroll
    for (int mm = 0; mm < 32; ++mm) {
      float4 kk = *(const float4*)&ks[mm][d1];
      float4 vv2 = *(const float4*)&vs[mm][d2];
      acc[0][0] = fmaf(kk.x, vv2.x, acc[0][0]);
      acc[0][1] = fmaf(kk.x, vv2.y, acc[0][1]);
      acc[0][2] = fmaf(kk.x, vv2.z, acc[0][2]);
      acc[0][3] = fmaf(kk.x, vv2.w, acc[0][3]);
      acc[1][0] = fmaf(kk.y, vv2.x, acc[1][0]);
      acc[1][1] = fmaf(kk.y, vv2.y, acc[1][1]);
      acc[1][2] = fmaf(kk.y, vv2.z, acc[1][2]);
      acc[1][3] = fmaf(kk.y, vv2.w, acc[1][3]);
      acc[2][0] = fmaf(kk.z, vv2.x, acc[2][0]);
      acc[2][1] = fmaf(kk.z, vv2.y, acc[2][1]);
      acc[2][2] = fmaf(kk.z, vv2.z, acc[2][2]);
      acc[2][3] = fmaf(kk.z, vv2.w, acc[2][3]);
      acc[3][0] = fmaf(kk.w, vv2.x, acc[3][0]);
      acc[3][1] = fmaf(kk.w, vv2.y, acc[3][1]);
      acc[3][2] = fmaf(kk.w, vv2.z, acc[3][2]);
      acc[3][3] = fmaf(kk.w, vv2.w, acc[3][3]);
    }
  }
  float* Sp = S4 + ((size_t)blockIdx.y * BH + bh) * DH * DH;
#pragma unroll
  for (int i = 0; i < 4; i++)
#pragma unroll
    for (int j = 0; j < 4; j++)
      Sp[(d1 + i) * DH + (d2 + j)] = acc[i][j];
}

// ---------------------------------------------------------------------------
// K4: ao[b, n, h*64+d2] = ((f_q[b,n,h,:] @ S[b,h]) * rq[b,n,h]) as fp16.
// S[b,h] = sum of the NSLC partial slices (summed during LDS staging).
// ---------------------------------------------------------------------------
__global__ void __launch_bounds__(256) outhead_kernel(
    const f16* __restrict__ f, const float* __restrict__ S4,
    const float* __restrict__ rq, f16* __restrict__ ao) {
  const int bh = blockIdx.x;
  const int b = bh >> 4, h = bh & 15;
  const int nbase = blockIdx.y * 64;
  const int t = threadIdx.x;
  __shared__ float Sl[64][68];
  __shared__ float Ql[64][68];
  {
    const int r = t >> 2;
    const int seg = (t & 3) * 16;
    const float* Sp = S4 + (size_t)bh * DH * DH + r * DH + seg;
    constexpr size_t STR = (size_t)BH * DH * DH;
#pragma unroll
    for (int c = 0; c < 4; c++) {
      float4 s = {0.f, 0.f, 0.f, 0.f};
#pragma unroll
      for (int p = 0; p < NSLC; p++) {
        float4 sp = ((const float4*)(Sp + p * STR))[c];
        s.x += sp.x; s.y += sp.y; s.z += sp.z; s.w += sp.w;
      }
      *(float4*)&Sl[r][seg + 4 * c] = s;
    }
    const f16* Qp = f + ((size_t)b * SEQQ + nbase + r) * DIM + h * DH + seg;
    f16x8 q0 = *(const f16x8*)Qp;
    f16x8 q1 = *(const f16x8*)(Qp + 8);
#pragma unroll
    for (int e = 0; e < 8; e++) {
      Ql[r][seg + e]     = (float)q0[e];
      Ql[r][seg + 8 + e] = (float)q1[e];
    }
  }
  __syncthreads();
  const int d2 = (t & 15) * 4;
  const int g  = t >> 4;
#pragma unroll
  for (int i = 0; i < 4; ++i) {
    const int n = i * 16 + g;
    float4 acc = {0.f, 0.f, 0.f, 0.f};
#pragma unroll 8
    for (int d1 = 0; d1 < 64; ++d1) {
      float qv = Ql[n][d1];
      float4 sv = *(const float4*)&Sl[d1][d2];
      acc.x = fmaf(qv, sv.x, acc.x);
      acc.y = fmaf(qv, sv.y, acc.y);
      acc.z = fmaf(qv, sv.z, acc.z);
      acc.w = fmaf(qv, sv.w, acc.w);
    }
    const float r = rq[((size_t)b * SEQQ + nbase + n) * NH + h];
    union { f16 h4[4]; uint2 u; } o;
    o.h4[0] = (f16)(acc.x * r);
    o.h4[1] = (f16)(acc.y * r);
    o.h4[2] = (f16)(acc.z * r);
    o.h4[3] = (f16)(acc.w * r);
    *(uint2*)(ao + ((size_t)b * SEQQ + nbase + n) * DIM + h * DH + d2) = o.u;
  }
}

// ---------------------------------------------------------------------------
extern "C" void kernel_launch(void* const* d_in, const int* in_sizes, int n_in,
                              void* d_out, int out_size, void* d_ws, size_t ws_size,
                              hipStream_t stream) {
  const float* q     = (const float*)d_in[0];
  const float* k     = (const float*)d_in[1];
  const float* v     = (const float*)d_in[2];
  const float* gamma = (const float*)d_in[3];
  const float* beta  = (const float*)d_in[4];
  const float* W_in  = (const float*)d_in[5];
  const float* W_out = (const float*)d_in[6];
  const float* b_out = (const float*)d_in[7];
  float* out = (float*)d_out;

  // workspace layout
  char* w = (char*)d_ws;
  f16*   f      = (f16*)w;                                     // 40 MB
  f16*   a_h    = f + (size_t)RTOT * DIM;                      // 40 MB
  f16*   wt_in  = a_h + (size_t)RTOT * DIM;                    // 2 MB
  f16*   wt_out = wt_in + (size_t)DIM * DIM;                   // 2 MB
  float* rqb    = (float*)(wt_out + (size_t)DIM * DIM);        // 256 KB
  float* rkb    = rqb + (size_t)RQ * NH;                       // 512 KB
  float* S4     = rkb + (size_t)RK * NH;                       // 8 MB
  f16*   ao     = a_h;  // alias: a_h dead after projection GEMM

  ln_to_f16<<<RTOT / 4, 256, 0, stream>>>(q, k, v, gamma, beta, a_h);
  transpose_f16<<<dim3(DIM / 32, DIM / 32, 2), 256, 0, stream>>>(
      W_in, W_out, wt_in, wt_out);

  // f = LN(t) @ W_in for all 20480 rows; fused per-head inverse norms
  mfma_gemm<128, true, true, false><<<dim3(RTOT / 128, DIM / 128), 256, 0, stream>>>(
      a_h, wt_in, f, nullptr, rqb, rkb);

  s_kernel<<<dim3(BH, NSLC), 256, 0, stream>>>(f, rkb, S4);

  outhead_kernel<<<dim3(BH, SEQQ / 64), 256, 0, stream>>>(f, S4, rqb, ao);

  // out = ao @ W_out + b_out  (MT=64: 512 blocks, 2/CU)
  mfma_gemm<64, false, false, true><<<dim3(RQ / 64, DIM / 128), 256, 0, stream>>>(
      ao, wt_out, out, b_out, nullptr, nullptr);
}

// Round 5
// 241.813 us; speedup vs baseline: 3.7834x; 1.0111x over previous
//
#include <hip/hip_runtime.h>

// Problem constants
constexpr int BATCH = 4;
constexpr int SEQQ  = 1024;
constexpr int SEQK  = 2048;
constexpr int DIM   = 1024;
constexpr int NH    = 16;
constexpr int DH    = 64;
constexpr int RQ    = BATCH * SEQQ;          // 4096 q rows
constexpr int RK    = BATCH * SEQK;          // 8192 k rows (== v rows)
constexpr int RTOT  = RQ + 2 * RK;           // 20480
constexpr int BH    = BATCH * NH;            // 64
constexpr int NSLC  = 8;                     // s_kernel K-slices
constexpr float LN_EPS = 1e-5f;

typedef _Float16 f16;
typedef __attribute__((ext_vector_type(8))) _Float16 f16x8;
typedef __attribute__((ext_vector_type(4))) float f32x4;

__device__ __forceinline__ void async16(const void* g, void* l) {
  __builtin_amdgcn_global_load_lds(
      (const __attribute__((address_space(1))) void*)g,
      (__attribute__((address_space(3))) void*)l, 16, 0, 0);
}

// ---------------------------------------------------------------------------
// K0: fused LayerNorm -> fp16. One wave per row (no LDS, no barriers).
// ---------------------------------------------------------------------------
__global__ void __launch_bounds__(256) ln_to_f16(
    const float* __restrict__ q, const float* __restrict__ k,
    const float* __restrict__ v, const float* __restrict__ gamma,
    const float* __restrict__ beta, f16* __restrict__ a_h) {
  const int row = blockIdx.x * 4 + (threadIdx.x >> 6);
  const int lane = threadIdx.x & 63;
  const float* src;
  if (row < RQ)            src = q + (size_t)row * DIM;
  else if (row < RQ + RK)  src = k + (size_t)(row - RQ) * DIM;
  else                     src = v + (size_t)(row - RQ - RK) * DIM;
  float4 x[4];
  float s = 0.f, s2 = 0.f;
#pragma unroll
  for (int c = 0; c < 4; c++) {
    x[c] = ((const float4*)src)[c * 64 + lane];
    s  += x[c].x + x[c].y + x[c].z + x[c].w;
    s2 += x[c].x * x[c].x + x[c].y * x[c].y + x[c].z * x[c].z + x[c].w * x[c].w;
  }
#pragma unroll
  for (int off = 1; off < 64; off <<= 1) {
    s  += __shfl_xor(s, off);
    s2 += __shfl_xor(s2, off);
  }
  const float mu = s / DIM;
  const float rs = rsqrtf(s2 / DIM - mu * mu + LN_EPS);
#pragma unroll
  for (int c = 0; c < 4; c++) {
    float4 g = ((const float4*)gamma)[c * 64 + lane];
    float4 b = ((const float4*)beta)[c * 64 + lane];
    union { f16 h[4]; uint2 u; } o;
    o.h[0] = (f16)((x[c].x - mu) * rs * g.x + b.x);
    o.h[1] = (f16)((x[c].y - mu) * rs * g.y + b.y);
    o.h[2] = (f16)((x[c].z - mu) * rs * g.z + b.z);
    o.h[3] = (f16)((x[c].w - mu) * rs * g.w + b.w);
    ((uint2*)(a_h + (size_t)row * DIM))[c * 64 + lane] = o.u;
  }
}

// ---------------------------------------------------------------------------
// K0b: transpose + fp16 convert of W_in and W_out (1024x1024 each).
// ---------------------------------------------------------------------------
__global__ void __launch_bounds__(256) transpose_f16(
    const float* __restrict__ W0, const float* __restrict__ W1,
    f16* __restrict__ T0, f16* __restrict__ T1) {
  const float* W = blockIdx.z ? W1 : W0;
  f16* T = blockIdx.z ? T1 : T0;
  __shared__ float tile[32][33];
  int tx = threadIdx.x & 31, ty = threadIdx.x >> 5;
  int k0 = blockIdx.x * 32, n0 = blockIdx.y * 32;
#pragma unroll
  for (int i = 0; i < 4; i++)
    tile[ty + 8 * i][tx] = W[(size_t)(k0 + ty + 8 * i) * DIM + n0 + tx];
  __syncthreads();
#pragma unroll
  for (int i = 0; i < 4; i++)
    T[(size_t)(n0 + ty + 8 * i) * DIM + k0 + tx] = (f16)tile[tx][ty + 8 * i];
}

// ---------------------------------------------------------------------------
// MFMA fp16 GEMM, C[M x 1024] = A[M x 1024] * Bt^T, Bt N-major [1024][1024].
// MT x 128 tile, BK=64 as two BK=32 sub-buffers, one barrier pair per 64-K.
// LDS chunk-rotation swizzle keeps fragment ds_read_b128 conflict-free.
// NORMS (MT=128, proj only): each wave's 64-col quadrant is one head —
// butterfly-reduce sum(x^2) per row across 16 lanes (all lanes get the
// total), then scale acc by rsqrt BEFORE the f16 store for q/k rows.
// f then holds g_q = f_q/||f_q|| and g_k = f_k/||f_k|| directly.
// PERB (final GEMM): Bt indexed per batch (row0>>10).
// ---------------------------------------------------------------------------
template <int MT, bool OUT_F16, bool NORMS, bool BIAS, bool PERB>
__global__ void __launch_bounds__(256) mfma_gemm(
    const f16* __restrict__ A, const f16* __restrict__ Bt,
    void* __restrict__ Cout, const float* __restrict__ bias) {
  constexpr int JT = (MT == 128) ? 4 : 2;
  __shared__ f16 As[2][MT * 32];
  __shared__ f16 Bs[2][128 * 32];
  const int t = threadIdx.x;
  const int wid = t >> 6;
  const int lane = t & 63;
  const int row0 = blockIdx.x * MT;
  const int col0 = blockIdx.y * 128;
  const int wm = (MT == 128) ? (wid >> 1) * 64 : 0;
  const int wn = (MT == 128) ? (wid & 1) * 64 : wid * 32;

  const f16* BtB = PERB ? Bt + (size_t)(row0 >> 10) * DIM * DIM : Bt;

  // staging pointers (chunk-rotation swizzle on the fetch column)
  const int rB = 32 * wid + (lane >> 2);
  const int qB = ((lane & 3) - ((rB >> 1) & 3)) & 3;
  const f16* gB = BtB + (size_t)(col0 + rB) * DIM + qB * 8;
  f16* lB0 = Bs[0] + 32 * wid * 32;
  f16* lB1 = Bs[1] + 32 * wid * 32;
  const int rA = (MT == 128 ? 32 : 16) * wid + (lane >> 2);
  const int qA = ((lane & 3) - ((rA >> 1) & 3)) & 3;
  const f16* gA = A + (size_t)(row0 + rA) * DIM + qA * 8;
  f16* lA0 = As[0] + (MT == 128 ? 32 : 16) * wid * 32;
  f16* lA1 = As[1] + (MT == 128 ? 32 : 16) * wid * 32;

  f32x4 acc[4][JT];
#pragma unroll
  for (int i = 0; i < 4; i++)
#pragma unroll
    for (int j = 0; j < JT; j++) acc[i][j] = (f32x4){0.f, 0.f, 0.f, 0.f};

  const int mrow = lane & 15;
  const int kq_p = (((lane >> 4) + ((lane >> 1) & 3)) & 3) * 8;

  for (int kt = 0; kt < DIM / 64; ++kt) {
    if (kt) __syncthreads();
    const int ko = kt * 64;
    async16(gA + ko,      lA0);
    if (MT == 128) async16(gA + ko + 16 * DIM, lA0 + 512);
    async16(gB + ko,      lB0);
    async16(gB + ko + 16 * DIM, lB0 + 512);
    async16(gA + ko + 32, lA1);
    if (MT == 128) async16(gA + ko + 32 + 16 * DIM, lA1 + 512);
    async16(gB + ko + 32, lB1);
    async16(gB + ko + 32 + 16 * DIM, lB1 + 512);
    __syncthreads();

#pragma unroll
    for (int h = 0; h < 2; ++h) {
      f16x8 af[4], bf[JT];
#pragma unroll
      for (int i = 0; i < 4; i++)
        af[i] = *(const f16x8*)(As[h] + (wm + i * 16 + mrow) * 32 + kq_p);
#pragma unroll
      for (int j = 0; j < JT; j++)
        bf[j] = *(const f16x8*)(Bs[h] + (wn + j * 16 + mrow) * 32 + kq_p);
#pragma unroll
      for (int i = 0; i < 4; i++)
#pragma unroll
        for (int j = 0; j < JT; j++)
          acc[i][j] = __builtin_amdgcn_mfma_f32_16x16x32_f16(af[i], bf[j], acc[i][j], 0, 0, 0);
    }
  }

  if (NORMS && MT == 128) {
    // pre-normalize q/k rows: sums over this wave's 64 cols (= one head)
    if (row0 < RQ + RK) {   // block-uniform: q or k rows
      float sums[4][4];
#pragma unroll
      for (int i = 0; i < 4; i++)
#pragma unroll
        for (int r = 0; r < 4; r++) {
          float s = 0.f;
#pragma unroll
          for (int j = 0; j < JT; j++) s += acc[i][j][r] * acc[i][j][r];
          sums[i][r] = s;
        }
#pragma unroll
      for (int off = 1; off < 16; off <<= 1)
#pragma unroll
        for (int i = 0; i < 4; i++)
#pragma unroll
          for (int r = 0; r < 4; r++)
            sums[i][r] += __shfl_xor(sums[i][r], off);
#pragma unroll
      for (int i = 0; i < 4; i++)
#pragma unroll
        for (int r = 0; r < 4; r++) {
          const float inv = rsqrtf(sums[i][r]);
#pragma unroll
          for (int j = 0; j < JT; j++) acc[i][j][r] *= inv;
        }
    }
  }

  // epilogue: C/D layout col=lane&15, row=(lane>>4)*4+reg
  const int ccol = lane & 15;
  const int crow = (lane >> 4) * 4;
  if (OUT_F16) {
    f16* C = (f16*)Cout;
#pragma unroll
    for (int j = 0; j < JT; j++) {
      const int col = col0 + wn + j * 16 + ccol;
#pragma unroll
      for (int i = 0; i < 4; i++) {
        f16* Cp = C + (size_t)(row0 + wm + i * 16 + crow) * DIM + col;
#pragma unroll
        for (int r = 0; r < 4; r++) Cp[(size_t)r * DIM] = (f16)acc[i][j][r];
      }
    }
  } else {
    float* C = (float*)Cout;
#pragma unroll
    for (int j = 0; j < JT; j++) {
      const int col = col0 + wn + j * 16 + ccol;
      float bv = BIAS ? bias[col] : 0.f;
#pragma unroll
      for (int i = 0; i < 4; i++) {
        float* Cp = C + (size_t)(row0 + wm + i * 16 + crow) * DIM + col;
#pragma unroll
        for (int r = 0; r < 4; r++) Cp[(size_t)r * DIM] = acc[i][j][r] + bv;
      }
    }
  }
}

// ---------------------------------------------------------------------------
// K3: per-(slice,b,h) partial S = sum over 256 m of g_k[m] outer f_v[m].
// g_k is pre-normalized (proj epilogue), so no per-row scale needed.
// ---------------------------------------------------------------------------
__global__ void __launch_bounds__(256) s_kernel(
    const f16* __restrict__ f, float* __restrict__ S4) {
  const int bh = blockIdx.x;
  const int b = bh >> 4, h = bh & 15;
  const int mbase = blockIdx.y * (SEQK / NSLC);
  const int t = threadIdx.x;
  __shared__ float ks[32][68];
  __shared__ float vs[32][68];
  const int lm   = t >> 3;
  const int lseg = (t & 7) * 8;
  const int d1 = (t & 15) * 4;
  const int d2 = (t >> 4) * 4;
  float acc[4][4] = {{0.f}};
  const f16* fk_base = f + ((size_t)RQ + (size_t)b * SEQK) * DIM + h * DH;
  const f16* fv_base = f + ((size_t)RQ + RK + (size_t)b * SEQK) * DIM + h * DH;

  int m = mbase + lm;
  f16x8 kv = *(const f16x8*)(fk_base + (size_t)m * DIM + lseg);
  f16x8 vv = *(const f16x8*)(fv_base + (size_t)m * DIM + lseg);

  constexpr int SUBS = SEQK / NSLC / 32;  // 8
  for (int sub = 0; sub < SUBS; ++sub) {
    __syncthreads();
#pragma unroll
    for (int e = 0; e < 8; e++) {
      ks[lm][lseg + e] = (float)kv[e];
      vs[lm][lseg + e] = (float)vv[e];
    }
    __syncthreads();
    if (sub + 1 < SUBS) {
      m = mbase + (sub + 1) * 32 + lm;
      kv = *(const f16x8*)(fk_base + (size_t)m * DIM + lseg);
      vv = *(const f16x8*)(fv_base + (size_t)m * DIM + lseg);
    }
#pragma unroll
    for (int mm = 0; mm < 32; ++mm) {
      float4 kk = *(const float4*)&ks[mm][d1];
      float4 vv2 = *(const float4*)&vs[mm][d2];
      acc[0][0] = fmaf(kk.x, vv2.x, acc[0][0]);
      acc[0][1] = fmaf(kk.x, vv2.y, acc[0][1]);
      acc[0][2] = fmaf(kk.x, vv2.z, acc[0][2]);
      acc[0][3] = fmaf(kk.x, vv2.w, acc[0][3]);
      acc[1][0] = fmaf(kk.y, vv2.x, acc[1][0]);
      acc[1][1] = fmaf(kk.y, vv2.y, acc[1][1]);
      acc[1][2] = fmaf(kk.y, vv2.z, acc[1][2]);
      acc[1][3] = fmaf(kk.y, vv2.w, acc[1][3]);
      acc[2][0] = fmaf(kk.z, vv2.x, acc[2][0]);
      acc[2][1] = fmaf(kk.z, vv2.y, acc[2][1]);
      acc[2][2] = fmaf(kk.z, vv2.z, acc[2][2]);
      acc[2][3] = fmaf(kk.z, vv2.w, acc[2][3]);
      acc[3][0] = fmaf(kk.w, vv2.x, acc[3][0]);
      acc[3][1] = fmaf(kk.w, vv2.y, acc[3][1]);
      acc[3][2] = fmaf(kk.w, vv2.z, acc[3][2]);
      acc[3][3] = fmaf(kk.w, vv2.w, acc[3][3]);
    }
  }
  float* Sp = S4 + ((size_t)blockIdx.y * BH + bh) * DH * DH;
#pragma unroll
  for (int i = 0; i < 4; i++)
#pragma unroll
    for (int j = 0; j < 4; j++)
      Sp[(d1 + i) * DH + (d2 + j)] = acc[i][j];
}

// ---------------------------------------------------------------------------
// K3b: sum the NSLC partial S slices -> Sh fp16 [bh][d1][d2] row-major.
// ---------------------------------------------------------------------------
__global__ void __launch_bounds__(256) s_reduce(
    const float* __restrict__ S4, f16* __restrict__ Sh) {
  const int bh = blockIdx.x;
  const int t = threadIdx.x;
  const size_t base = (size_t)bh * DH * DH + t * 16;
  constexpr size_t STR = (size_t)BH * DH * DH;
#pragma unroll
  for (int c = 0; c < 4; c++) {
    float4 s = {0.f, 0.f, 0.f, 0.f};
#pragma unroll
    for (int p = 0; p < NSLC; p++) {
      float4 sp = *(const float4*)(S4 + base + p * STR + 4 * c);
      s.x += sp.x; s.y += sp.y; s.z += sp.z; s.w += sp.w;
    }
    union { f16 h[4]; uint2 u; } o;
    o.h[0] = (f16)s.x; o.h[1] = (f16)s.y; o.h[2] = (f16)s.z; o.h[3] = (f16)s.w;
    *(uint2*)(Sh + base + 4 * c) = o.u;
  }
}

// ---------------------------------------------------------------------------
// K3c: Mt[b][n][64h+d1] = sum_d2 wt_out[n][64h+d2] * Sh[b,h][d1][d2]
// i.e. Mt_block = wt_out_slice(128x64) @ Sh^T via MFMA; both operands are
// already in the required layouts (A row-major, Bt N-major = Sh row-major).
// grid (8 n-blocks, 64 bh). Single K pass (K=64).
// ---------------------------------------------------------------------------
__global__ void __launch_bounds__(256) m_build(
    const f16* __restrict__ wt_out, const f16* __restrict__ Sh,
    f16* __restrict__ Mt) {
  const int n0 = blockIdx.x * 128;
  const int bh = blockIdx.y;
  const int b = bh >> 4, h = bh & 15;
  __shared__ f16 As[128 * 64];
  __shared__ f16 Bs[64 * 64];
  const int t = threadIdx.x;
  const int wid = t >> 6, lane = t & 63;

  // A staging: wave w stages rows [32w, 32w+32), 4 instrs x 8 rows each
  const f16* gA = wt_out + (size_t)(n0 + 32 * wid + (lane >> 3)) * DIM
                  + 64 * h + (lane & 7) * 8;
  f16* lA = As + 32 * wid * 64;
  // B staging: wave w stages rows [16w, 16w+16), 2 instrs x 8 rows each
  const f16* gB = Sh + (size_t)bh * DH * DH + (16 * wid + (lane >> 3)) * 64
                  + (lane & 7) * 8;
  f16* lB = Bs + 16 * wid * 64;
#pragma unroll
  for (int o = 0; o < 4; o++) async16(gA + (size_t)(8 * o) * DIM, lA + 8 * o * 64);
  async16(gB, lB);
  async16(gB + 8 * 64, lB + 8 * 64);
  __syncthreads();

  const int wm = (wid >> 1) * 64;   // n-dim block
  const int wn = (wid & 1) * 32;    // d1-dim block
  const int mrow = lane & 15;
  f32x4 acc[4][2];
#pragma unroll
  for (int i = 0; i < 4; i++)
#pragma unroll
    for (int j = 0; j < 2; j++) acc[i][j] = (f32x4){0.f, 0.f, 0.f, 0.f};

#pragma unroll
  for (int kh = 0; kh < 2; kh++) {
    const int kq = kh * 32 + (lane >> 4) * 8;
    f16x8 af[4], bf[2];
#pragma unroll
    for (int i = 0; i < 4; i++)
      af[i] = *(const f16x8*)(As + (wm + i * 16 + mrow) * 64 + kq);
#pragma unroll
    for (int j = 0; j < 2; j++)
      bf[j] = *(const f16x8*)(Bs + (wn + j * 16 + mrow) * 64 + kq);
#pragma unroll
    for (int i = 0; i < 4; i++)
#pragma unroll
      for (int j = 0; j < 2; j++)
        acc[i][j] = __builtin_amdgcn_mfma_f32_16x16x32_f16(af[i], bf[j], acc[i][j], 0, 0, 0);
  }

  const int ccol = lane & 15;
  const int crow = (lane >> 4) * 4;
  f16* Mb = Mt + (size_t)b * DIM * DIM;
#pragma unroll
  for (int j = 0; j < 2; j++) {
    const int col = 64 * h + wn + j * 16 + ccol;
#pragma unroll
    for (int i = 0; i < 4; i++) {
      f16* Mp = Mb + (size_t)(n0 + wm + i * 16 + crow) * DIM + col;
#pragma unroll
      for (int r = 0; r < 4; r++) Mp[(size_t)r * DIM] = (f16)acc[i][j][r];
    }
  }
}

// ---------------------------------------------------------------------------
extern "C" void kernel_launch(void* const* d_in, const int* in_sizes, int n_in,
                              void* d_out, int out_size, void* d_ws, size_t ws_size,
                              hipStream_t stream) {
  const float* q     = (const float*)d_in[0];
  const float* k     = (const float*)d_in[1];
  const float* v     = (const float*)d_in[2];
  const float* gamma = (const float*)d_in[3];
  const float* beta  = (const float*)d_in[4];
  const float* W_in  = (const float*)d_in[5];
  const float* W_out = (const float*)d_in[6];
  const float* b_out = (const float*)d_in[7];
  float* out = (float*)d_out;

  // workspace layout
  char* w = (char*)d_ws;
  f16*   f      = (f16*)w;                                     // 40 MB
  f16*   a_h    = f + (size_t)RTOT * DIM;                      // 40 MB
  f16*   wt_in  = a_h + (size_t)RTOT * DIM;                    // 2 MB
  f16*   wt_out = wt_in + (size_t)DIM * DIM;                   // 2 MB
  f16*   Mt     = wt_out + (size_t)DIM * DIM;                  // 8 MB
  f16*   Sh     = Mt + (size_t)BATCH * DIM * DIM;              // 512 KB
  float* S4     = (float*)(Sh + (size_t)BH * DH * DH);         // 8 MB

  ln_to_f16<<<RTOT / 4, 256, 0, stream>>>(q, k, v, gamma, beta, a_h);
  transpose_f16<<<dim3(DIM / 32, DIM / 32, 2), 256, 0, stream>>>(
      W_in, W_out, wt_in, wt_out);

  // f = LN(t) @ W_in for all rows; q/k rows pre-normalized per head
  mfma_gemm<128, true, true, false, false>
      <<<dim3(RTOT / 128, DIM / 128), 256, 0, stream>>>(a_h, wt_in, f, nullptr);

  s_kernel<<<dim3(BH, NSLC), 256, 0, stream>>>(f, S4);

  s_reduce<<<BH, 256, 0, stream>>>(S4, Sh);

  m_build<<<dim3(DIM / 128, BH), 256, 0, stream>>>(wt_out, Sh, Mt);

  // out = g_q @ Mt[b]^T + b_out (per-batch weights)
  mfma_gemm<64, false, false, true, true>
      <<<dim3(RQ / 64, DIM / 128), 256, 0, stream>>>(f, Mt, out, b_out);
}